// Round 5
// baseline (6003.391 us; speedup 1.0000x reference)
//
#include <hip/hip_runtime.h>
#include <cstdint>
#include <cstddef>

#define B_  1024
#define T_  100
#define H_  256

typedef _Float16 f16x8 __attribute__((ext_vector_type(8)));
typedef float    f32x16 __attribute__((ext_vector_type(16)));

__device__ __forceinline__ float sigm(float x){ return 1.0f/(1.0f + __expf(-x)); }
__device__ __forceinline__ float tanh_(float x){ return 1.0f - 2.0f/(1.0f + __expf(2.0f*x)); }

// fp16 fragment-major weight pool offsets (elements).
// Frag layout per pool: fid = ((cc*4+g)*nkk + kk)*64 + lane, holding
// W[g*256 + cc*32 + (lane&31)][kk*16 + (lane>>5)*8 + 0..7]  (f16x8 per lane).
#define W_WHH1F 0
#define W_WHH1B 262144
#define W_WIH2F 524288
#define W_WIH2B 1048576
#define W_WHH2F 1572864
#define W_WHH2B 1835008
#define W_TOTAL 2097152

__global__ void pack_weights(const float* __restrict__ Whh1f, const float* __restrict__ Whh1b,
                             const float* __restrict__ Wih2f, const float* __restrict__ Wih2b,
                             const float* __restrict__ Whh2f, const float* __restrict__ Whh2b,
                             _Float16* __restrict__ dst)
{
  int fid = blockIdx.x*256 + threadIdx.x;   // 0 .. 262143 frags
  const float* src; int base, nkk, ksh, lf;
  if      (fid <  32768){ src=Whh1f; base=W_WHH1F; nkk=16; ksh=4; lf=fid; }
  else if (fid <  65536){ src=Whh1b; base=W_WHH1B; nkk=16; ksh=4; lf=fid-32768; }
  else if (fid < 131072){ src=Wih2f; base=W_WIH2F; nkk=32; ksh=5; lf=fid-65536; }
  else if (fid < 196608){ src=Wih2b; base=W_WIH2B; nkk=32; ksh=5; lf=fid-131072; }
  else if (fid < 229376){ src=Whh2f; base=W_WHH2F; nkk=16; ksh=4; lf=fid-196608; }
  else                  { src=Whh2b; base=W_WHH2B; nkk=16; ksh=4; lf=fid-229376; }
  int l  = lf & 63;
  int t  = lf >> 6;
  int kk = t & (nkk-1);
  int r  = t >> ksh;           // cc*4+g
  int g  = r & 3, cc = r >> 2;
  int K  = nkk*16;
  int n  = g*256 + cc*32 + (l & 31);
  int k  = kk*16 + ((l >> 5) << 3);
  const float4* s4 = (const float4*)(src + (size_t)n*K + k);
  float4 v0 = s4[0], v1 = s4[1];
  f16x8 o;
  o[0]=(_Float16)v0.x; o[1]=(_Float16)v0.y; o[2]=(_Float16)v0.z; o[3]=(_Float16)v0.w;
  o[4]=(_Float16)v1.x; o[5]=(_Float16)v1.y; o[6]=(_Float16)v1.z; o[7]=(_Float16)v1.w;
  *(f16x8*)(dst + (size_t)base + (size_t)lf*8) = o;
}

// ---------------- L1 persistent phase (block-local recurrence) ----------------
// 64 blocks x 512 threads (8 waves). Block (dir, rc) owns batch rows
// [rc*32, +32) and computes ALL 256 h-columns each step -> the recurrence
// never leaves the block. h kept in LDS in MFMA A-fragment layout
// ([kk][lane][8] fp16, 16KB, conflict-free ds_read_b128); c in registers.
// Weights are read fragment-major directly from global each step: 8 blocks
// per XCD share a 1MB working set -> L2-resident after step 0.
// Wave w owns h-cols [w*32,+32) x 4 gates (4 MFMA 32x32 tiles, acc=64 VGPR).
__global__ __launch_bounds__(512, 2)
void l1_phase(const _Float16* __restrict__ wpool,
              const float* __restrict__ Wih_f, const float* __restrict__ Wih_b,
              const float* __restrict__ bih_f, const float* __restrict__ bhh_f,
              const float* __restrict__ bih_b, const float* __restrict__ bhh_b,
              const float* __restrict__ x0, const float* __restrict__ mvec,
              const float* __restrict__ mask1, const float* __restrict__ mask2,
              _Float16* __restrict__ p1m)     // [T][B][512] fp16 (h*mask2)
{
  __shared__ __align__(16) _Float16 hlds[8192];   // 16KB: [kk][lane][8]
  const int bid = blockIdx.x;                     // 64 blocks
  const int dir = bid >> 5, rc = bid & 31;
  const int tid = threadIdx.x, lane = tid & 63, w = tid >> 6;
  const int b0 = rc*32;
  const int hcol = w*32 + (lane & 31);
  const _Float16* whh = wpool + (dir ? W_WHH1B : W_WHH1F);

  #pragma unroll
  for (int i = 0; i < 16; i++) hlds[tid + 512*i] = (_Float16)0.f;

  const float* Wih = dir ? Wih_b : Wih_f;
  const float* bih = dir ? bih_b : bih_f;
  const float* bhh = dir ? bhh_b : bhh_f;
  float wi0[4], wi1[4], bs[4];
  #pragma unroll
  for (int g = 0; g < 4; g++){
    int n = g*256 + hcol;
    wi0[g] = Wih[n*2]; wi1[g] = Wih[n*2 + 1];
    bs[g]  = bih[n] + bhh[n];
  }
  int rowv[16]; float m1v[16], m2v[16], mvv[16], creg[16];
  #pragma unroll
  for (int r = 0; r < 16; r++){
    int row = (r & 3) + 8*(r >> 2) + 4*(lane >> 5);
    rowv[r] = row;
    int b = b0 + row;
    m1v[r] = mask1[(size_t)b*H_ + hcol];
    m2v[r] = mask2[(size_t)b*512 + dir*256 + hcol];
    mvv[r] = mvec[b];
    creg[r] = 0.0f;
  }
  // h value at (row m, col k) lives at elem (k>>4)*512 + ((k>>3)&1)*256 + m*8 + (k&7)
  const int wbase = (hcol >> 4)*512 + ((hcol >> 3) & 1)*256 + (hcol & 7);
  __syncthreads();

  for (int s = 0; s < T_; s++){
    const int tin = dir ? (T_-1-s) : s;
    f32x16 acc[4];
    #pragma unroll
    for (int g = 0; g < 4; g++)
      #pragma unroll
      for (int e = 0; e < 16; e++) acc[g][e] = 0.0f;

    #pragma unroll 4
    for (int kk = 0; kk < 16; kk++){
      f16x8 a = *(const f16x8*)(hlds + kk*512 + lane*8);
      #pragma unroll
      for (int g = 0; g < 4; g++){
        f16x8 bw = *(const f16x8*)(whh + (size_t)(((w*4 + g)*16 + kk)*512 + lane*8));
        acc[g] = __builtin_amdgcn_mfma_f32_32x32x16_f16(a, bw, acc[g], 0, 0, 0);
      }
    }
    __syncthreads();     // all hlds reads done before overwrite

    #pragma unroll
    for (int r = 0; r < 16; r++){
      int b = b0 + rowv[r];
      float mv = mvv[r];
      float xd = x0[b*T_ + tin] - mv;
      float gi = acc[0][r] + xd*wi0[0] + mv*wi1[0] + bs[0];
      float gf = acc[1][r] + xd*wi0[1] + mv*wi1[1] + bs[1];
      float gg = acc[2][r] + xd*wi0[2] + mv*wi1[2] + bs[2];
      float go = acc[3][r] + xd*wi0[3] + mv*wi1[3] + bs[3];
      float ii = sigm(gi), ff = sigm(gf), g2 = tanh_(gg), oo = sigm(go);
      float cn = ff*creg[r] + ii*g2;
      creg[r] = cn;
      float h = oo*tanh_(cn);
      hlds[wbase + rowv[r]*8] = (_Float16)(h * m1v[r]);
      p1m[((size_t)s*B_ + b)*512 + dir*256 + hcol] = (_Float16)(h * m2v[r]);
    }
    __syncthreads();     // hlds fully written before next step's reads
  }
}

// ---------------- L2 persistent phase (block-local recurrence) ----------------
// Same decomposition. Per step: recurrent GEMM (K=256, A from LDS) +
// input GEMM (K=512, A-fragments read directly from p1m in global).
// Weights direct from L2 (3MB working set per XCD).
__global__ __launch_bounds__(512, 2)
void l2_phase(const _Float16* __restrict__ wpool,
              const float* __restrict__ bih_f, const float* __restrict__ bhh_f,
              const float* __restrict__ bih_b, const float* __restrict__ bhh_b,
              const _Float16* __restrict__ p1m,
              const float* __restrict__ mask3, const float* __restrict__ mask4,
              const float* __restrict__ Wout,
              float* __restrict__ pred)
{
  __shared__ __align__(16) _Float16 hlds[8192];
  const int bid = blockIdx.x;
  const int dir = bid >> 5, rc = bid & 31;
  const int tid = threadIdx.x, lane = tid & 63, w = tid >> 6;
  const int b0 = rc*32;
  const int hcol = w*32 + (lane & 31);
  const _Float16* whh = wpool + (dir ? W_WHH2B : W_WHH2F);
  const _Float16* wih = wpool + (dir ? W_WIH2B : W_WIH2F);

  #pragma unroll
  for (int i = 0; i < 16; i++) hlds[tid + 512*i] = (_Float16)0.f;

  const float* bih = dir ? bih_b : bih_f;
  const float* bhh = dir ? bhh_b : bhh_f;
  float bs[4];
  #pragma unroll
  for (int g = 0; g < 4; g++) bs[g] = bih[g*256 + hcol] + bhh[g*256 + hcol];
  float wo = Wout[dir*256 + hcol];
  int rowv[16]; float m3v[16], m4v[16], creg[16];
  #pragma unroll
  for (int r = 0; r < 16; r++){
    int row = (r & 3) + 8*(r >> 2) + 4*(lane >> 5);
    rowv[r] = row;
    int b = b0 + row;
    m3v[r] = mask3[(size_t)b*H_ + hcol];
    m4v[r] = mask4[(size_t)b*512 + dir*256 + hcol] * wo;
    creg[r] = 0.0f;
  }
  const int wbase = (hcol >> 4)*512 + ((hcol >> 3) & 1)*256 + (hcol & 7);
  __syncthreads();

  for (int s = 0; s < T_; s++){
    const int tin = dir ? (T_-1-s) : s;
    f32x16 acc[4];
    #pragma unroll
    for (int g = 0; g < 4; g++)
      #pragma unroll
      for (int e = 0; e < 16; e++) acc[g][e] = 0.0f;

    // recurrent GEMM: K=256, A from LDS, B = Whh2 fragments from global
    #pragma unroll 4
    for (int kk = 0; kk < 16; kk++){
      f16x8 a = *(const f16x8*)(hlds + kk*512 + lane*8);
      #pragma unroll
      for (int g = 0; g < 4; g++){
        f16x8 bw = *(const f16x8*)(whh + (size_t)(((w*4 + g)*16 + kk)*512 + lane*8));
        acc[g] = __builtin_amdgcn_mfma_f32_32x32x16_f16(a, bw, acc[g], 0, 0, 0);
      }
    }
    // input GEMM: K=512, A-fragments straight from p1m, B = Wih2 fragments
    const _Float16* arow2 = p1m + ((size_t)tin*B_ + b0 + (lane & 31))*512 + ((lane >> 5) << 3);
    #pragma unroll 4
    for (int kk = 0; kk < 32; kk++){
      f16x8 a = *(const f16x8*)(arow2 + kk*16);
      #pragma unroll
      for (int g = 0; g < 4; g++){
        f16x8 bw = *(const f16x8*)(wih + (size_t)(((w*4 + g)*32 + kk)*512 + lane*8));
        acc[g] = __builtin_amdgcn_mfma_f32_32x32x16_f16(a, bw, acc[g], 0, 0, 0);
      }
    }
    __syncthreads();     // hlds reads done

    #pragma unroll
    for (int r = 0; r < 16; r++){
      int b = b0 + rowv[r];
      float gi = acc[0][r] + bs[0];
      float gf = acc[1][r] + bs[1];
      float gg = acc[2][r] + bs[2];
      float go = acc[3][r] + bs[3];
      float ii = sigm(gi), ff = sigm(gf), g2 = tanh_(gg), oo = sigm(go);
      float cn = ff*creg[r] + ii*g2;
      creg[r] = cn;
      float h = oo*tanh_(cn);
      hlds[wbase + rowv[r]*8] = (_Float16)(h * m3v[r]);
      float contrib = h * m4v[r];
      contrib += __shfl_xor(contrib, 16);
      contrib += __shfl_xor(contrib, 8);
      contrib += __shfl_xor(contrib, 4);
      contrib += __shfl_xor(contrib, 2);
      contrib += __shfl_xor(contrib, 1);
      if ((lane & 31) == 0) atomicAdd(&pred[(size_t)b*T_ + s], contrib);
    }
    __syncthreads();
  }
}

__global__ void prep_kernel(const float* __restrict__ x0, float* __restrict__ mvec)
{
  int b = blockIdx.x*blockDim.x + threadIdx.x;
  if (b < B_){
    float ssum = 0.0f;
    for (int t = 0; t < T_; t++) ssum += x0[b*T_ + t];
    mvec[b] = ssum * (1.0f / T_);
  }
}

__global__ void final_kernel(const float* __restrict__ pred,
                             const float* __restrict__ mvec,
                             const float* __restrict__ bout,
                             float* __restrict__ out)
{
  int idx = blockIdx.x*256 + threadIdx.x;
  if (idx < B_*T_){
    int b = idx / T_;
    out[idx] = pred[idx] + bout[0] + mvec[b];
  }
}

extern "C" void kernel_launch(void* const* d_in, const int* in_sizes, int n_in,
                              void* d_out, int out_size, void* d_ws, size_t ws_size,
                              hipStream_t stream)
{
  (void)in_sizes; (void)n_in; (void)out_size; (void)ws_size;
  const float* x0    = (const float*)d_in[0];
  const float* Wih1f = (const float*)d_in[1];
  const float* Whh1f = (const float*)d_in[2];
  const float* bih1f = (const float*)d_in[3];
  const float* bhh1f = (const float*)d_in[4];
  const float* Wih1b = (const float*)d_in[5];
  const float* Whh1b = (const float*)d_in[6];
  const float* bih1b = (const float*)d_in[7];
  const float* bhh1b = (const float*)d_in[8];
  const float* Wih2f = (const float*)d_in[9];
  const float* Whh2f = (const float*)d_in[10];
  const float* bih2f = (const float*)d_in[11];
  const float* bhh2f = (const float*)d_in[12];
  const float* Wih2b = (const float*)d_in[13];
  const float* Whh2b = (const float*)d_in[14];
  const float* bih2b = (const float*)d_in[15];
  const float* bhh2b = (const float*)d_in[16];
  const float* Wout  = (const float*)d_in[17];
  const float* bout  = (const float*)d_in[18];
  const float* mask1 = (const float*)d_in[19];
  const float* mask2 = (const float*)d_in[20];
  const float* mask3 = (const float*)d_in[21];
  const float* mask4 = (const float*)d_in[22];
  float* out = (float*)d_out;

  // Workspace layout (~110 MB)
  char* ws = (char*)d_ws;
  size_t off = 0;
  _Float16* wpool = (_Float16*)(ws + off); off += (size_t)W_TOTAL*2;        // 4.2 MB
  _Float16* p1m   = (_Float16*)(ws + off); off += (size_t)T_*B_*512*2;      // 104.8 MB
  float* pred = (float*)(ws + off); off += (size_t)B_*T_*4;                 // 0.4 MB
  float* mvec = (float*)(ws + off); off += 4096;

  hipMemsetAsync(pred, 0, (size_t)B_*T_*4, stream);

  pack_weights<<<dim3(1024), dim3(256), 0, stream>>>(
      Whh1f, Whh1b, Wih2f, Wih2b, Whh2f, Whh2b, wpool);
  prep_kernel<<<dim3(4), dim3(256), 0, stream>>>(x0, mvec);

  l1_phase<<<dim3(64), dim3(512), 0, stream>>>(wpool, Wih1f, Wih1b,
      bih1f, bhh1f, bih1b, bhh1b, x0, mvec, mask1, mask2, p1m);
  l2_phase<<<dim3(64), dim3(512), 0, stream>>>(wpool, bih2f, bhh2f,
      bih2b, bhh2b, p1m, mask3, mask4, Wout, pred);
  final_kernel<<<dim3((B_*T_ + 255)/256), dim3(256), 0, stream>>>(pred, mvec, bout, out);
}